// Round 1
// baseline (2246.827 us; speedup 1.0000x reference)
//
#include <hip/hip_runtime.h>
#include <cstddef>
#include <cstdint>

static constexpr int F_IN  = 512;
static constexpr int F_H   = 128;
static constexpr int F_OUT = 40;

// ---------------- degree / normalization ----------------
__global__ void k_deg_init(float* deg, int N) {
  int i = blockIdx.x * blockDim.x + threadIdx.x;
  if (i < N) deg[i] = 1.0f;  // self-loop
}

__global__ void k_deg_count(const int* __restrict__ dst, float* deg, int E) {
  int e = blockIdx.x * blockDim.x + threadIdx.x;
  if (e < E) atomicAdd(&deg[dst[e]], 1.0f);
}

__global__ void k_dinv(float* deg, int N) {
  int i = blockIdx.x * blockDim.x + threadIdx.x;
  if (i < N) deg[i] = rsqrtf(deg[i]);  // deg >= 1 always
}

// ---------------- GEMM1: h = x @ W1  (N x 512 @ 512 x 128) ----------------
// 128 threads/block (one per output feature), 16 node-rows per block.
// x tile staged in LDS; W1 reads coalesced (512B per k across the block).
__global__ void k_gemm1(const float* __restrict__ x, const float* __restrict__ W,
                        float* __restrict__ h, int N) {
  __shared__ float xt[16][32];
  const int f  = threadIdx.x;        // 0..127
  const int n0 = blockIdx.x * 16;
  float acc[16];
#pragma unroll
  for (int i = 0; i < 16; ++i) acc[i] = 0.f;

  for (int k0 = 0; k0 < F_IN; k0 += 32) {
    __syncthreads();
#pragma unroll
    for (int i = 0; i < 4; ++i) {
      int idx = threadIdx.x + i * 128;   // 0..511
      int n = idx >> 5, kk = idx & 31;
      int row = n0 + n; if (row >= N) row = N - 1;  // N%16==0 here, safe anyway
      xt[n][kk] = x[(size_t)row * F_IN + k0 + kk];
    }
    __syncthreads();
#pragma unroll
    for (int kk = 0; kk < 32; ++kk) {
      float w = W[(size_t)(k0 + kk) * F_H + f];
#pragma unroll
      for (int i = 0; i < 16; ++i) acc[i] += xt[i][kk] * w;  // LDS broadcast
    }
  }
#pragma unroll
  for (int i = 0; i < 16; ++i) {
    int row = n0 + i;
    if (row < N) h[(size_t)row * F_H + f] = acc[i];
  }
}

// ---------------- self-loop term (also initializes the output buffer) ------
template <int F>
__global__ void k_selfloop(const float* __restrict__ h, const float* __restrict__ dinv,
                           float* __restrict__ out, int total) {
  int i = blockIdx.x * blockDim.x + threadIdx.x;
  if (i >= total) return;
  int n = i / F;
  float di = dinv[n];
  out[i] = h[i] * (di * di);
}

// ---------------- edge aggregation: out[dst] += h[src] * dinv[s]*dinv[d] ---
// 1 thread = 1 edge x 4 features (float4 gather, 4 scalar atomics).
template <int F>
__global__ void k_edge_agg(const float* __restrict__ h, const float* __restrict__ dinv,
                           const int* __restrict__ src, const int* __restrict__ dst,
                           float* __restrict__ out, int E) {
  constexpr int PER = F / 4;
  int gid = blockIdx.x * blockDim.x + threadIdx.x;
  int e = gid / PER;
  if (e >= E) return;
  int f = (gid - e * PER) * 4;
  int s = src[e], d = dst[e];
  float nrm = dinv[s] * dinv[d];
  const float4 hv = *reinterpret_cast<const float4*>(h + (size_t)s * F + f);
  float* o = out + (size_t)d * F + f;
  atomicAdd(o + 0, hv.x * nrm);
  atomicAdd(o + 1, hv.y * nrm);
  atomicAdd(o + 2, hv.z * nrm);
  atomicAdd(o + 3, hv.w * nrm);
}

// ---------------- bias + ReLU (layer 1) ----------------
template <int F>  // F must be a power of two
__global__ void k_bias_relu(float* a, const float* __restrict__ b, int total) {
  int i = blockIdx.x * blockDim.x + threadIdx.x;
  if (i >= total) return;
  float v = a[i] + b[i & (F - 1)];
  a[i] = fmaxf(v, 0.f);
}

// ---------------- GEMM2: h2 = a1 @ W2  (N x 128 @ 128 x 40) ----------------
__global__ void k_gemm2(const float* __restrict__ a, const float* __restrict__ W,
                        float* __restrict__ h2, int total) {
  int i = blockIdx.x * blockDim.x + threadIdx.x;
  if (i >= total) return;
  int n = i / F_OUT, c = i - n * F_OUT;
  const float* ar = a + (size_t)n * F_H;
  float acc = 0.f;
#pragma unroll 4
  for (int k = 0; k < F_H; ++k) acc += ar[k] * W[k * F_OUT + c];
  h2[i] = acc;
}

// ---------------- +b2 then log_softmax over 40 classes, in place ----------
__global__ void k_logsm(float* __restrict__ out, const float* __restrict__ b2, int N) {
  int t = blockIdx.x * blockDim.x + threadIdx.x;
  int n = t >> 6, lane = t & 63;
  if (n >= N) return;
  float val = 0.f, m = -3.0e38f;
  if (lane < F_OUT) { val = out[(size_t)n * F_OUT + lane] + b2[lane]; m = val; }
#pragma unroll
  for (int off = 32; off > 0; off >>= 1) m = fmaxf(m, __shfl_xor(m, off));
  float ex = (lane < F_OUT) ? expf(val - m) : 0.f;
#pragma unroll
  for (int off = 32; off > 0; off >>= 1) ex += __shfl_xor(ex, off);
  float ls = logf(ex);
  if (lane < F_OUT) out[(size_t)n * F_OUT + lane] = val - m - ls;
}

extern "C" void kernel_launch(void* const* d_in, const int* in_sizes, int n_in,
                              void* d_out, int out_size, void* d_ws, size_t ws_size,
                              hipStream_t stream) {
  const float* x  = (const float*)d_in[0];
  const int*   ei = (const int*)d_in[1];   // edge_index, int -> int32 per harness
  const float* W1 = (const float*)d_in[2];
  const float* b1 = (const float*)d_in[3];
  const float* W2 = (const float*)d_in[4];
  const float* b2 = (const float*)d_in[5];

  const int N = in_sizes[0] / F_IN;   // 50000
  const int E = in_sizes[1] / 2;      // 800000
  const int* src = ei;
  const int* dst = ei + E;

  // workspace layout (floats): dinv | h1 | a1 | h2   (~59.5 MB total)
  float* ws   = (float*)d_ws;
  float* dinv = ws;
  float* h1   = ws + (((size_t)N + 1023) & ~(size_t)1023);
  float* a1   = h1 + (size_t)N * F_H;
  float* h2   = a1 + (size_t)N * F_H;
  float* outp = (float*)d_out;

  const int B = 256;
  k_deg_init <<<(N + B - 1) / B, B, 0, stream>>>(dinv, N);
  k_deg_count<<<(E + B - 1) / B, B, 0, stream>>>(dst, dinv, E);
  k_dinv     <<<(N + B - 1) / B, B, 0, stream>>>(dinv, N);

  k_gemm1<<<(N + 15) / 16, 128, 0, stream>>>(x, W1, h1, N);

  int tot1 = N * F_H;   // 6.4M
  k_selfloop<F_H><<<(tot1 + B - 1) / B, B, 0, stream>>>(h1, dinv, a1, tot1);
  {
    long long threads = (long long)E * (F_H / 4);
    k_edge_agg<F_H><<<(int)((threads + B - 1) / B), B, 0, stream>>>(h1, dinv, src, dst, a1, E);
  }
  k_bias_relu<F_H><<<(tot1 + B - 1) / B, B, 0, stream>>>(a1, b1, tot1);

  int tot2 = N * F_OUT; // 2.0M
  k_gemm2<<<(tot2 + B - 1) / B, B, 0, stream>>>(a1, W2, h2, tot2);
  k_selfloop<F_OUT><<<(tot2 + B - 1) / B, B, 0, stream>>>(h2, dinv, outp, tot2);
  {
    long long threads = (long long)E * (F_OUT / 4);
    k_edge_agg<F_OUT><<<(int)((threads + B - 1) / B), B, 0, stream>>>(h2, dinv, src, dst, outp, E);
  }
  k_logsm<<<((N * 64) + B - 1) / B, B, 0, stream>>>(outp, b2, N);
}

// Round 2
// 567.985 us; speedup vs baseline: 3.9558x; 3.9558x over previous
//
#include <hip/hip_runtime.h>
#include <cstddef>
#include <cstdint>

static constexpr int F_IN  = 512;
static constexpr int F_H   = 128;
static constexpr int F_OUT = 40;

// ---------------- CSR build ----------------
__global__ void k_zero_i32(int* p, int n) {
  int i = blockIdx.x * blockDim.x + threadIdx.x;
  if (i < n) p[i] = 0;
}

__global__ void k_count(const int* __restrict__ dst, int* __restrict__ cnt, int E) {
  int e = blockIdx.x * blockDim.x + threadIdx.x;
  if (e < E) atomicAdd(&cnt[dst[e]], 1);
}

__global__ void k_dinv_from_cnt(const int* __restrict__ cnt, float* __restrict__ dinv, int N) {
  int i = blockIdx.x * blockDim.x + threadIdx.x;
  if (i < N) dinv[i] = rsqrtf((float)cnt[i] + 1.0f);  // +1 self-loop
}

// single-block exclusive scan over N counts -> row_ptr[0..N]
__global__ void k_scan(const int* __restrict__ cnt, int* __restrict__ row_ptr, int N, int E) {
  __shared__ int tmp[1024];
  __shared__ int carry;
  if (threadIdx.x == 0) carry = 0;
  __syncthreads();
  for (int base = 0; base < N; base += 1024) {
    int i = base + threadIdx.x;
    int v = (i < N) ? cnt[i] : 0;
    tmp[threadIdx.x] = v;
    __syncthreads();
    for (int off = 1; off < 1024; off <<= 1) {
      int t = (threadIdx.x >= off) ? tmp[threadIdx.x - off] : 0;
      __syncthreads();
      tmp[threadIdx.x] += t;
      __syncthreads();
    }
    if (i < N) row_ptr[i] = carry + tmp[threadIdx.x] - v;  // exclusive
    __syncthreads();
    if (threadIdx.x == 1023) carry += tmp[1023];
    __syncthreads();
  }
  if (threadIdx.x == 0) row_ptr[N] = E;
}

__global__ void k_scatter(const int* __restrict__ src, const int* __restrict__ dst,
                          const int* __restrict__ row_ptr, int* __restrict__ cursor,
                          int* __restrict__ src_sorted, int E) {
  int e = blockIdx.x * blockDim.x + threadIdx.x;
  if (e >= E) return;
  int d = dst[e];
  int pos = row_ptr[d] + atomicAdd(&cursor[d], 1);
  src_sorted[pos] = src[e];
}

// ---------------- GEMM1: h = x @ W1  (N x 512 @ 512 x 128) ----------------
__global__ void k_gemm1(const float* __restrict__ x, const float* __restrict__ W,
                        float* __restrict__ h, int N) {
  __shared__ float xt[16][32];
  const int f  = threadIdx.x;        // 0..127
  const int n0 = blockIdx.x * 16;
  float acc[16];
#pragma unroll
  for (int i = 0; i < 16; ++i) acc[i] = 0.f;

  for (int k0 = 0; k0 < F_IN; k0 += 32) {
    __syncthreads();
#pragma unroll
    for (int i = 0; i < 4; ++i) {
      int idx = threadIdx.x + i * 128;   // 0..511
      int n = idx >> 5, kk = idx & 31;
      int row = n0 + n; if (row >= N) row = N - 1;
      xt[n][kk] = x[(size_t)row * F_IN + k0 + kk];
    }
    __syncthreads();
#pragma unroll
    for (int kk = 0; kk < 32; ++kk) {
      float w = W[(size_t)(k0 + kk) * F_H + f];
#pragma unroll
      for (int i = 0; i < 16; ++i) acc[i] += xt[i][kk] * w;
    }
  }
#pragma unroll
  for (int i = 0; i < 16; ++i) {
    int row = n0 + i;
    if (row < N) h[(size_t)row * F_H + f] = acc[i];
  }
}

// ---------------- CSR gather aggregation, no atomics ----------------
// CPN = F/4 consecutive threads own one node; each holds a float4 slice.
// acc init = self-loop; epilogue fuses bias (+ReLU for layer 1).
template <int F, bool RELU>
__global__ void k_agg(const float* __restrict__ h, const float* __restrict__ dinv,
                      const int* __restrict__ row_ptr, const int* __restrict__ src_sorted,
                      const float* __restrict__ bias, float* __restrict__ out, int N) {
  constexpr int CPN = F / 4;
  int gid = blockIdx.x * blockDim.x + threadIdx.x;
  int n = gid / CPN;
  if (n >= N) return;
  int f = (gid - n * CPN) * 4;

  float dn = dinv[n];
  float4 acc = *reinterpret_cast<const float4*>(h + (size_t)n * F + f);
  float sl = dn * dn;
  acc.x *= sl; acc.y *= sl; acc.z *= sl; acc.w *= sl;

  int beg = row_ptr[n], end = row_ptr[n + 1];
  for (int j = beg; j < end; ++j) {
    int s = src_sorted[j];
    float nrm = dinv[s] * dn;
    float4 hv = *reinterpret_cast<const float4*>(h + (size_t)s * F + f);
    acc.x += hv.x * nrm;
    acc.y += hv.y * nrm;
    acc.z += hv.z * nrm;
    acc.w += hv.w * nrm;
  }

  float4 bv = *reinterpret_cast<const float4*>(bias + f);
  acc.x += bv.x; acc.y += bv.y; acc.z += bv.z; acc.w += bv.w;
  if (RELU) {
    acc.x = fmaxf(acc.x, 0.f); acc.y = fmaxf(acc.y, 0.f);
    acc.z = fmaxf(acc.z, 0.f); acc.w = fmaxf(acc.w, 0.f);
  }
  *reinterpret_cast<float4*>(out + (size_t)n * F + f) = acc;
}

// ---------------- GEMM2: h2 = a1 @ W2  (N x 128 @ 128 x 40) ----------------
__global__ void k_gemm2(const float* __restrict__ a, const float* __restrict__ W,
                        float* __restrict__ h2, int total) {
  int i = blockIdx.x * blockDim.x + threadIdx.x;
  if (i >= total) return;
  int n = i / F_OUT, c = i - n * F_OUT;
  const float* ar = a + (size_t)n * F_H;
  float acc = 0.f;
#pragma unroll 4
  for (int k = 0; k < F_H; ++k) acc += ar[k] * W[k * F_OUT + c];
  h2[i] = acc;
}

// ---------------- log_softmax over 40 classes, in place (bias pre-added) --
__global__ void k_logsm(float* __restrict__ out, int N) {
  int t = blockIdx.x * blockDim.x + threadIdx.x;
  int n = t >> 6, lane = t & 63;
  if (n >= N) return;
  float val = 0.f, m = -3.0e38f;
  if (lane < F_OUT) { val = out[(size_t)n * F_OUT + lane]; m = val; }
#pragma unroll
  for (int off = 32; off > 0; off >>= 1) m = fmaxf(m, __shfl_xor(m, off));
  float ex = (lane < F_OUT) ? expf(val - m) : 0.f;
#pragma unroll
  for (int off = 32; off > 0; off >>= 1) ex += __shfl_xor(ex, off);
  float ls = logf(ex);
  if (lane < F_OUT) out[(size_t)n * F_OUT + lane] = val - m - ls;
}

extern "C" void kernel_launch(void* const* d_in, const int* in_sizes, int n_in,
                              void* d_out, int out_size, void* d_ws, size_t ws_size,
                              hipStream_t stream) {
  const float* x  = (const float*)d_in[0];
  const int*   ei = (const int*)d_in[1];
  const float* W1 = (const float*)d_in[2];
  const float* b1 = (const float*)d_in[3];
  const float* W2 = (const float*)d_in[4];
  const float* b2 = (const float*)d_in[5];

  const int N = in_sizes[0] / F_IN;   // 50000
  const int E = in_sizes[1] / 2;      // 800000
  const int* src = ei;
  const int* dst = ei + E;

  // workspace layout (4-byte words):
  // dinv[pad N] | h1[N*128] | a1[N*128] | cnt[N] | row_ptr[N+1] | cursor[N] | src_sorted[E]
  // h2 reuses h1's space (h1 dead after agg1).
  float* ws   = (float*)d_ws;
  size_t Npad = ((size_t)N + 1023) & ~(size_t)1023;
  float* dinv = ws;
  float* h1   = ws + Npad;
  float* a1   = h1 + (size_t)N * F_H;
  int*   cnt      = (int*)(a1 + (size_t)N * F_H);
  int*   row_ptr  = cnt + Npad;
  int*   cursor   = row_ptr + Npad;
  int*   src_sorted = cursor + Npad;
  float* h2   = h1;                    // reuse
  float* outp = (float*)d_out;

  const int B = 256;
  // CSR build
  k_zero_i32<<<(N + B - 1) / B, B, 0, stream>>>(cnt, N);
  k_count   <<<(E + B - 1) / B, B, 0, stream>>>(dst, cnt, E);
  k_dinv_from_cnt<<<(N + B - 1) / B, B, 0, stream>>>(cnt, dinv, N);
  k_scan    <<<1, 1024, 0, stream>>>(cnt, row_ptr, N, E);
  k_zero_i32<<<(N + B - 1) / B, B, 0, stream>>>(cursor, N);
  k_scatter <<<(E + B - 1) / B, B, 0, stream>>>(src, dst, row_ptr, cursor, src_sorted, E);

  // layer 1
  k_gemm1<<<(N + 15) / 16, 128, 0, stream>>>(x, W1, h1, N);
  {
    long long threads = (long long)N * (F_H / 4);
    k_agg<F_H, true><<<(int)((threads + B - 1) / B), B, 0, stream>>>(
        h1, dinv, row_ptr, src_sorted, b1, a1, N);
  }

  // layer 2
  int tot2 = N * F_OUT;
  k_gemm2<<<(tot2 + B - 1) / B, B, 0, stream>>>(a1, W2, h2, tot2);
  {
    long long threads = (long long)N * (F_OUT / 4);
    k_agg<F_OUT, false><<<(int)((threads + B - 1) / B), B, 0, stream>>>(
        h2, dinv, row_ptr, src_sorted, b2, outp, N);
  }
  k_logsm<<<((N * 64) + B - 1) / B, B, 0, stream>>>(outp, N);
}

// Round 3
// 303.764 us; speedup vs baseline: 7.3966x; 1.8698x over previous
//
#include <hip/hip_runtime.h>
#include <cstddef>
#include <cstdint>

typedef __attribute__((ext_vector_type(8))) short short8;
typedef __attribute__((ext_vector_type(4))) float f32x4;

static constexpr int F_IN  = 512;
static constexpr int F_H   = 128;
static constexpr int F_OUT = 40;

__device__ inline unsigned short f2bf(float f) {
  uint32_t u = __builtin_bit_cast(uint32_t, f);
  u = (u + 0x7FFFu + ((u >> 16) & 1u)) >> 16;
  return (unsigned short)u;
}
__device__ inline float bf2f(uint32_t lo16) {
  return __builtin_bit_cast(float, lo16 << 16);
}
__device__ inline void bf8_to_f32(uint4 u, float* o) {
  o[0] = bf2f(u.x & 0xFFFFu); o[1] = bf2f(u.x >> 16);
  o[2] = bf2f(u.y & 0xFFFFu); o[3] = bf2f(u.y >> 16);
  o[4] = bf2f(u.z & 0xFFFFu); o[5] = bf2f(u.z >> 16);
  o[6] = bf2f(u.w & 0xFFFFu); o[7] = bf2f(u.w >> 16);
}

// ---------------- CSR build ----------------
__global__ void k_zero_i32(int* p, int n) {
  int i = blockIdx.x * blockDim.x + threadIdx.x;
  if (i < n) p[i] = 0;
}

__global__ void k_count(const int* __restrict__ dst, int* __restrict__ cnt, int E) {
  int e = blockIdx.x * blockDim.x + threadIdx.x;
  if (e < E) atomicAdd(&cnt[dst[e]], 1);
}

__global__ void k_dinv_from_cnt(const int* __restrict__ cnt, float* __restrict__ dinv, int N) {
  int i = blockIdx.x * blockDim.x + threadIdx.x;
  if (i < N) dinv[i] = rsqrtf((float)cnt[i] + 1.0f);
}

// 3-phase parallel exclusive scan (N up to 50176 with 49 blocks x 1024)
__global__ void k_scan_local(const int* __restrict__ cnt, int* __restrict__ rp,
                             int* __restrict__ bsum, int N) {
  __shared__ int tmp[1024];
  int t = threadIdx.x;
  int i = blockIdx.x * 1024 + t;
  int v = (i < N) ? cnt[i] : 0;
  tmp[t] = v;
  __syncthreads();
  for (int off = 1; off < 1024; off <<= 1) {
    int u = (t >= off) ? tmp[t - off] : 0;
    __syncthreads();
    tmp[t] += u;
    __syncthreads();
  }
  if (i < N) rp[i] = tmp[t] - v;
  if (t == 1023) bsum[blockIdx.x] = tmp[1023];
}

__global__ void k_scan_carry(int* bsum, int nb) {
  if (threadIdx.x == 0 && blockIdx.x == 0) {
    int run = 0;
    for (int b = 0; b < nb; ++b) { int v = bsum[b]; bsum[b] = run; run += v; }
  }
}

__global__ void k_scan_add(int* __restrict__ rp, const int* __restrict__ bsum, int N, int E) {
  int i = blockIdx.x * blockDim.x + threadIdx.x;
  if (i < N) rp[i] += bsum[i >> 10];
  if (i == N) rp[N] = E;
}

__global__ void k_scatter(const int* __restrict__ src, const int* __restrict__ dst,
                          const int* __restrict__ row_ptr, int* __restrict__ cursor,
                          int* __restrict__ src_sorted, int E) {
  int e = blockIdx.x * blockDim.x + threadIdx.x;
  if (e >= E) return;
  int d = dst[e];
  int pos = row_ptr[d] + atomicAdd(&cursor[d], 1);
  src_sorted[pos] = src[e];
}

// ---------------- W1 [512][128] f32  ->  W1t [128][512] bf16 ----------------
__global__ void k_wconv(const float* __restrict__ W, unsigned short* __restrict__ Wt) {
  int i = blockIdx.x * blockDim.x + threadIdx.x;   // i over 128*512
  if (i >= F_H * F_IN) return;
  int f = i >> 9, k = i & 511;
  Wt[i] = f2bf(W[(size_t)k * F_H + f]);
}

// ---------------- GEMM1 (MFMA bf16): h = x @ W1, h stored bf16 -------------
// BM=64 nodes, BN=128 feats, BK=64. 128 threads = 2 waves, wave w: rows w*32..+31.
// LDS tiles XOR-chunk-swizzled: chunk (row, lc) stored at pc = lc ^ (row&7).
__global__ __launch_bounds__(128) void k_gemm1(const float* __restrict__ x,
                                               const unsigned short* __restrict__ Wt,
                                               unsigned short* __restrict__ h, int N) {
  __shared__ unsigned short At[64][64];    // [row][k]  8 KB
  __shared__ unsigned short Bt[128][64];   // [feat][k] 16 KB
  const int t    = threadIdx.x;
  const int lane = t & 63;
  const int w    = t >> 6;
  const int n0   = blockIdx.x * 64;

  f32x4 acc[2][8];
#pragma unroll
  for (int i = 0; i < 2; ++i)
#pragma unroll
    for (int j = 0; j < 8; ++j) acc[i][j] = (f32x4){0.f, 0.f, 0.f, 0.f};

  for (int k0 = 0; k0 < F_IN; k0 += 64) {
    __syncthreads();
    // stage A: 64 rows x 8 chunks, in-register f32->bf16 conversion
#pragma unroll
    for (int rep = 0; rep < 4; ++rep) {
      int c = rep * 128 + t;
      int row = c >> 3, lc = c & 7;
      int gr = n0 + row; if (gr >= N) gr = N - 1;
      const float* gp = x + (size_t)gr * F_IN + k0 + lc * 8;
      float4 lo = *(const float4*)gp;
      float4 hi = *(const float4*)(gp + 4);
      short8 v;
      v[0] = (short)f2bf(lo.x); v[1] = (short)f2bf(lo.y);
      v[2] = (short)f2bf(lo.z); v[3] = (short)f2bf(lo.w);
      v[4] = (short)f2bf(hi.x); v[5] = (short)f2bf(hi.y);
      v[6] = (short)f2bf(hi.z); v[7] = (short)f2bf(hi.w);
      *(short8*)&At[row][(lc ^ (row & 7)) * 8] = v;
    }
    // stage B: 128 rows x 8 chunks from bf16 W1t
#pragma unroll
    for (int rep = 0; rep < 8; ++rep) {
      int c = rep * 128 + t;
      int row = c >> 3, lc = c & 7;
      uint4 bv = *(const uint4*)(Wt + (size_t)row * F_IN + k0 + lc * 8);
      *(uint4*)&Bt[row][(lc ^ (row & 7)) * 8] = bv;
    }
    __syncthreads();

#pragma unroll
    for (int ks = 0; ks < 2; ++ks) {
      const int lcf = ks * 4 + (lane >> 4);
      short8 af[2], bfr[8];
#pragma unroll
      for (int fr = 0; fr < 2; ++fr) {
        int r = w * 32 + fr * 16 + (lane & 15);
        af[fr] = *(const short8*)&At[r][(lcf ^ (r & 7)) * 8];
      }
#pragma unroll
      for (int fc = 0; fc < 8; ++fc) {
        int r = fc * 16 + (lane & 15);
        bfr[fc] = *(const short8*)&Bt[r][(lcf ^ (r & 7)) * 8];
      }
#pragma unroll
      for (int fr = 0; fr < 2; ++fr)
#pragma unroll
        for (int fc = 0; fc < 8; ++fc)
          acc[fr][fc] = __builtin_amdgcn_mfma_f32_16x16x32_bf16(af[fr], bfr[fc], acc[fr][fc], 0, 0, 0);
    }
  }

  // C write (bf16): col = fc*16 + (lane&15), row = base + (lane>>4)*4 + j
#pragma unroll
  for (int fr = 0; fr < 2; ++fr) {
    int rbase = n0 + w * 32 + fr * 16 + ((lane >> 4) << 2);
#pragma unroll
    for (int fc = 0; fc < 8; ++fc) {
      int col = fc * 16 + (lane & 15);
#pragma unroll
      for (int j = 0; j < 4; ++j) {
        int r = rbase + j;
        if (r < N) h[(size_t)r * F_H + col] = f2bf(acc[fr][fc][j]);
      }
    }
  }
}

// ---------------- CSR gather agg on bf16 h (128-wide), fused bias+ReLU -----
__global__ void k_agg128(const unsigned short* __restrict__ h, const float* __restrict__ dinv,
                         const int* __restrict__ row_ptr, const int* __restrict__ srcs,
                         const float* __restrict__ bias, float* __restrict__ out, int N) {
  int gid = blockIdx.x * blockDim.x + threadIdx.x;
  int n = gid >> 4;
  if (n >= N) return;
  int f = (gid & 15) * 8;

  float dn = dinv[n];
  float acc[8], tmp[8];
  uint4 sv = *(const uint4*)(h + (size_t)n * F_H + f);
  bf8_to_f32(sv, tmp);
  float sl = dn * dn;
#pragma unroll
  for (int i = 0; i < 8; ++i) acc[i] = tmp[i] * sl;

  int beg = row_ptr[n], end = row_ptr[n + 1];
  for (int j = beg; j < end; ++j) {
    int s = srcs[j];
    float nr = dinv[s] * dn;
    uint4 hv = *(const uint4*)(h + (size_t)s * F_H + f);
    bf8_to_f32(hv, tmp);
#pragma unroll
    for (int i = 0; i < 8; ++i) acc[i] += tmp[i] * nr;
  }

#pragma unroll
  for (int i = 0; i < 8; ++i) {
    acc[i] += bias[f + i];
    acc[i] = fmaxf(acc[i], 0.f);
  }
  float4 o0 = {acc[0], acc[1], acc[2], acc[3]};
  float4 o1 = {acc[4], acc[5], acc[6], acc[7]};
  *(float4*)(out + (size_t)n * F_H + f)     = o0;
  *(float4*)(out + (size_t)n * F_H + f + 4) = o1;
}

// ---------------- GEMM2: h2 = a1 @ W2  (N x 128 @ 128 x 40), f32 ----------
__global__ void k_gemm2(const float* __restrict__ a, const float* __restrict__ W,
                        float* __restrict__ h2, int total) {
  int i = blockIdx.x * blockDim.x + threadIdx.x;
  if (i >= total) return;
  int n = i / F_OUT, c = i - n * F_OUT;
  const float4* ar = (const float4*)(a + (size_t)n * F_H);
  float acc = 0.f;
#pragma unroll
  for (int k4 = 0; k4 < F_H / 4; ++k4) {
    float4 av = ar[k4];
    const float* wr = W + (size_t)(k4 * 4) * F_OUT + c;
    acc += av.x * wr[0] + av.y * wr[F_OUT] + av.z * wr[2 * F_OUT] + av.w * wr[3 * F_OUT];
  }
  h2[i] = acc;
}

// ---------------- CSR gather agg f32 (40-wide), fused +b2 ------------------
__global__ void k_agg40(const float* __restrict__ h, const float* __restrict__ dinv,
                        const int* __restrict__ row_ptr, const int* __restrict__ srcs,
                        const float* __restrict__ bias, float* __restrict__ out, int N) {
  constexpr int CPN = F_OUT / 4;  // 10
  int gid = blockIdx.x * blockDim.x + threadIdx.x;
  int n = gid / CPN;
  if (n >= N) return;
  int f = (gid - n * CPN) * 4;

  float dn = dinv[n];
  float4 acc = *reinterpret_cast<const float4*>(h + (size_t)n * F_OUT + f);
  float sl = dn * dn;
  acc.x *= sl; acc.y *= sl; acc.z *= sl; acc.w *= sl;

  int beg = row_ptr[n], end = row_ptr[n + 1];
  for (int j = beg; j < end; ++j) {
    int s = srcs[j];
    float nr = dinv[s] * dn;
    float4 hv = *reinterpret_cast<const float4*>(h + (size_t)s * F_OUT + f);
    acc.x += hv.x * nr; acc.y += hv.y * nr; acc.z += hv.z * nr; acc.w += hv.w * nr;
  }
  float4 bv = *reinterpret_cast<const float4*>(bias + f);
  acc.x += bv.x; acc.y += bv.y; acc.z += bv.z; acc.w += bv.w;
  *reinterpret_cast<float4*>(out + (size_t)n * F_OUT + f) = acc;
}

// ---------------- log_softmax over 40 classes, in place --------------------
__global__ void k_logsm(float* __restrict__ out, int N) {
  int t = blockIdx.x * blockDim.x + threadIdx.x;
  int n = t >> 6, lane = t & 63;
  if (n >= N) return;
  float val = 0.f, m = -3.0e38f;
  if (lane < F_OUT) { val = out[(size_t)n * F_OUT + lane]; m = val; }
#pragma unroll
  for (int off = 32; off > 0; off >>= 1) m = fmaxf(m, __shfl_xor(m, off));
  float ex = (lane < F_OUT) ? expf(val - m) : 0.f;
#pragma unroll
  for (int off = 32; off > 0; off >>= 1) ex += __shfl_xor(ex, off);
  float ls = logf(ex);
  if (lane < F_OUT) out[(size_t)n * F_OUT + lane] = val - m - ls;
}

extern "C" void kernel_launch(void* const* d_in, const int* in_sizes, int n_in,
                              void* d_out, int out_size, void* d_ws, size_t ws_size,
                              hipStream_t stream) {
  const float* x  = (const float*)d_in[0];
  const int*   ei = (const int*)d_in[1];
  const float* W1 = (const float*)d_in[2];
  const float* b1 = (const float*)d_in[3];
  const float* W2 = (const float*)d_in[4];
  const float* b2 = (const float*)d_in[5];

  const int N = in_sizes[0] / F_IN;   // 50000
  const int E = in_sizes[1] / 2;      // 800000
  const int* src = ei;
  const int* dst = ei + E;

  // workspace layout (4-byte words)
  float* ws   = (float*)d_ws;
  size_t Npad = ((size_t)N + 1023) & ~(size_t)1023;          // 50176
  float*          dinv   = ws;
  unsigned short* h1b    = (unsigned short*)(ws + Npad);     // N*128 bf16 = N*64 words
  float*          a1     = ws + Npad + (size_t)N * (F_H / 2);
  float*          h2     = a1 + (size_t)N * F_H;
  int*            cnt    = (int*)(h2 + (size_t)N * F_OUT);
  int*            row_ptr= cnt + Npad;
  int*            cursor = row_ptr + Npad;
  int*            src_sorted = cursor + Npad;
  unsigned short* W1t    = (unsigned short*)(src_sorted + E); // 128*512 bf16
  int*            bsum   = (int*)(W1t + (size_t)F_H * F_IN);
  float*          outp   = (float*)d_out;

  const int B = 256;
  const int nscan = (N + 1023) / 1024;  // 49

  // CSR build + norm
  k_zero_i32<<<(N + B - 1) / B, B, 0, stream>>>(cnt, N);
  k_count   <<<(E + B - 1) / B, B, 0, stream>>>(dst, cnt, E);
  k_dinv_from_cnt<<<(N + B - 1) / B, B, 0, stream>>>(cnt, dinv, N);
  k_scan_local<<<nscan, 1024, 0, stream>>>(cnt, row_ptr, bsum, N);
  k_scan_carry<<<1, 64, 0, stream>>>(bsum, nscan);
  k_scan_add  <<<(N + 1 + B - 1) / B, B, 0, stream>>>(row_ptr, bsum, N, E);
  k_zero_i32<<<(N + B - 1) / B, B, 0, stream>>>(cursor, N);
  k_scatter <<<(E + B - 1) / B, B, 0, stream>>>(src, dst, row_ptr, cursor, src_sorted, E);

  // weights prep
  k_wconv<<<(F_H * F_IN + B - 1) / B, B, 0, stream>>>(W1, W1t);

  // layer 1: bf16 MFMA GEMM -> bf16 h1 -> gather agg (+bias+ReLU) -> f32 a1
  k_gemm1<<<(N + 63) / 64, 128, 0, stream>>>(x, W1t, h1b, N);
  {
    long long threads = (long long)N * 16;
    k_agg128<<<(int)((threads + B - 1) / B), B, 0, stream>>>(h1b, dinv, row_ptr, src_sorted, b1, a1, N);
  }

  // layer 2: f32 GEMM -> gather agg (+b2) -> log_softmax
  int tot2 = N * F_OUT;
  k_gemm2<<<(tot2 + B - 1) / B, B, 0, stream>>>(a1, W2, h2, tot2);
  {
    long long threads = (long long)N * (F_OUT / 4);
    k_agg40<<<(int)((threads + B - 1) / B), B, 0, stream>>>(h2, dinv, row_ptr, src_sorted, b2, outp, N);
  }
  k_logsm<<<((size_t)N * 64 + B - 1) / B, B, 0, stream>>>(outp, N);
}

// Round 4
// 228.016 us; speedup vs baseline: 9.8538x; 1.3322x over previous
//
#include <hip/hip_runtime.h>
#include <cstddef>
#include <cstdint>

typedef __attribute__((ext_vector_type(8))) short short8;
typedef __attribute__((ext_vector_type(4))) float f32x4;

static constexpr int F_IN  = 512;
static constexpr int F_H   = 128;
static constexpr int F_OUT = 40;
static constexpr int F_OP  = 48;   // padded output cols for MFMA

__device__ inline unsigned short f2bf(float f) {
  uint32_t u = __builtin_bit_cast(uint32_t, f);
  u = (u + 0x7FFFu + ((u >> 16) & 1u)) >> 16;
  return (unsigned short)u;
}
__device__ inline float bf2f(uint32_t lo16) {
  return __builtin_bit_cast(float, lo16 << 16);
}
__device__ inline void bf8_to_f32(uint4 u, float* o) {
  o[0] = bf2f(u.x & 0xFFFFu); o[1] = bf2f(u.x >> 16);
  o[2] = bf2f(u.y & 0xFFFFu); o[3] = bf2f(u.y >> 16);
  o[4] = bf2f(u.z & 0xFFFFu); o[5] = bf2f(u.z >> 16);
  o[6] = bf2f(u.w & 0xFFFFu); o[7] = bf2f(u.w >> 16);
}

// ---------------- CSR build ----------------
__global__ void k_zero_i32(int* p, int n) {
  int i = blockIdx.x * blockDim.x + threadIdx.x;
  if (i < n) p[i] = 0;
}

__global__ void k_count(const int* __restrict__ dst, int* __restrict__ cnt, int E) {
  int e = blockIdx.x * blockDim.x + threadIdx.x;
  if (e < E) atomicAdd(&cnt[dst[e]], 1);
}

__global__ void k_dinv_from_cnt(const int* __restrict__ cnt, float* __restrict__ dinv, int N) {
  int i = blockIdx.x * blockDim.x + threadIdx.x;
  if (i < N) dinv[i] = rsqrtf((float)cnt[i] + 1.0f);
}

__global__ void k_scan_local(const int* __restrict__ cnt, int* __restrict__ rp,
                             int* __restrict__ bsum, int N) {
  __shared__ int tmp[1024];
  int t = threadIdx.x;
  int i = blockIdx.x * 1024 + t;
  int v = (i < N) ? cnt[i] : 0;
  tmp[t] = v;
  __syncthreads();
  for (int off = 1; off < 1024; off <<= 1) {
    int u = (t >= off) ? tmp[t - off] : 0;
    __syncthreads();
    tmp[t] += u;
    __syncthreads();
  }
  if (i < N) rp[i] = tmp[t] - v;
  if (t == 1023) bsum[blockIdx.x] = tmp[1023];
}

__global__ void k_scan_carry(int* bsum, int nb) {
  if (threadIdx.x == 0 && blockIdx.x == 0) {
    int run = 0;
    for (int b = 0; b < nb; ++b) { int v = bsum[b]; bsum[b] = run; run += v; }
  }
}

__global__ void k_scan_add(int* __restrict__ rp, const int* __restrict__ bsum, int N, int E) {
  int i = blockIdx.x * blockDim.x + threadIdx.x;
  if (i < N) rp[i] += bsum[i >> 10];
  if (i == N) rp[N] = E;
}

__global__ void k_scatter(const int* __restrict__ src, const int* __restrict__ dst,
                          const int* __restrict__ row_ptr, int* __restrict__ cursor,
                          int* __restrict__ src_sorted, int E) {
  int e = blockIdx.x * blockDim.x + threadIdx.x;
  if (e >= E) return;
  int d = dst[e];
  int pos = row_ptr[d] + atomicAdd(&cursor[d], 1);
  src_sorted[pos] = src[e];
}

// ---------------- W1 [512][128] f32 -> W1t [128][512] bf16 -----------------
__global__ void k_wconv(const float* __restrict__ W, unsigned short* __restrict__ Wt) {
  int i = blockIdx.x * blockDim.x + threadIdx.x;
  if (i >= F_H * F_IN) return;
  int f = i >> 9, k = i & 511;
  Wt[i] = f2bf(W[(size_t)k * F_H + f]);
}

// ---------------- W2 [128][40] f32 -> W2t [48][128] bf16 (zero-padded) -----
__global__ void k_w2conv(const float* __restrict__ W, unsigned short* __restrict__ Wt) {
  int i = blockIdx.x * blockDim.x + threadIdx.x;
  if (i >= F_OP * F_H) return;
  int c = i >> 7, k = i & 127;
  float v = (c < F_OUT) ? W[(size_t)k * F_OUT + c] : 0.f;
  Wt[i] = f2bf(v);
}

// ---------------- GEMM1 (MFMA bf16): h = x @ W1, h stored bf16 -------------
__global__ __launch_bounds__(128) void k_gemm1(const float* __restrict__ x,
                                               const unsigned short* __restrict__ Wt,
                                               unsigned short* __restrict__ h, int N) {
  __shared__ unsigned short At[64][64];
  __shared__ unsigned short Bt[128][64];
  const int t    = threadIdx.x;
  const int lane = t & 63;
  const int w    = t >> 6;
  const int n0   = blockIdx.x * 64;

  f32x4 acc[2][8];
#pragma unroll
  for (int i = 0; i < 2; ++i)
#pragma unroll
    for (int j = 0; j < 8; ++j) acc[i][j] = (f32x4){0.f, 0.f, 0.f, 0.f};

  for (int k0 = 0; k0 < F_IN; k0 += 64) {
    __syncthreads();
#pragma unroll
    for (int rep = 0; rep < 4; ++rep) {
      int c = rep * 128 + t;
      int row = c >> 3, lc = c & 7;
      int gr = n0 + row; if (gr >= N) gr = N - 1;
      const float* gp = x + (size_t)gr * F_IN + k0 + lc * 8;
      float4 lo = *(const float4*)gp;
      float4 hi = *(const float4*)(gp + 4);
      short8 v;
      v[0] = (short)f2bf(lo.x); v[1] = (short)f2bf(lo.y);
      v[2] = (short)f2bf(lo.z); v[3] = (short)f2bf(lo.w);
      v[4] = (short)f2bf(hi.x); v[5] = (short)f2bf(hi.y);
      v[6] = (short)f2bf(hi.z); v[7] = (short)f2bf(hi.w);
      *(short8*)&At[row][(lc ^ (row & 7)) * 8] = v;
    }
#pragma unroll
    for (int rep = 0; rep < 8; ++rep) {
      int c = rep * 128 + t;
      int row = c >> 3, lc = c & 7;
      uint4 bv = *(const uint4*)(Wt + (size_t)row * F_IN + k0 + lc * 8);
      *(uint4*)&Bt[row][(lc ^ (row & 7)) * 8] = bv;
    }
    __syncthreads();

#pragma unroll
    for (int ks = 0; ks < 2; ++ks) {
      const int lcf = ks * 4 + (lane >> 4);
      short8 af[2], bfr[8];
#pragma unroll
      for (int fr = 0; fr < 2; ++fr) {
        int r = w * 32 + fr * 16 + (lane & 15);
        af[fr] = *(const short8*)&At[r][(lcf ^ (r & 7)) * 8];
      }
#pragma unroll
      for (int fc = 0; fc < 8; ++fc) {
        int r = fc * 16 + (lane & 15);
        bfr[fc] = *(const short8*)&Bt[r][(lcf ^ (r & 7)) * 8];
      }
#pragma unroll
      for (int fr = 0; fr < 2; ++fr)
#pragma unroll
        for (int fc = 0; fc < 8; ++fc)
          acc[fr][fc] = __builtin_amdgcn_mfma_f32_16x16x32_bf16(af[fr], bfr[fc], acc[fr][fc], 0, 0, 0);
    }
  }

#pragma unroll
  for (int fr = 0; fr < 2; ++fr) {
    int rbase = n0 + w * 32 + fr * 16 + ((lane >> 4) << 2);
#pragma unroll
    for (int fc = 0; fc < 8; ++fc) {
      int col = fc * 16 + (lane & 15);
#pragma unroll
      for (int j = 0; j < 4; ++j) {
        int r = rbase + j;
        if (r < N) h[(size_t)r * F_H + col] = f2bf(acc[fr][fc][j]);
      }
    }
  }
}

// ---------------- CSR gather agg bf16->bf16 (128-wide), fused bias+ReLU ----
__global__ void k_agg128(const unsigned short* __restrict__ h, const float* __restrict__ dinv,
                         const int* __restrict__ row_ptr, const int* __restrict__ srcs,
                         const float* __restrict__ bias, unsigned short* __restrict__ out, int N) {
  int gid = blockIdx.x * blockDim.x + threadIdx.x;
  int n = gid >> 4;
  if (n >= N) return;
  int f = (gid & 15) * 8;

  float dn = dinv[n];
  float acc[8], tmp[8];
  uint4 sv = *(const uint4*)(h + (size_t)n * F_H + f);
  bf8_to_f32(sv, tmp);
  float sl = dn * dn;
#pragma unroll
  for (int i = 0; i < 8; ++i) acc[i] = tmp[i] * sl;

  int beg = row_ptr[n], end = row_ptr[n + 1];
  int j = beg;
  for (; j + 1 < end; j += 2) {
    int s0 = srcs[j], s1 = srcs[j + 1];
    float nr0 = dinv[s0] * dn, nr1 = dinv[s1] * dn;
    uint4 h0 = *(const uint4*)(h + (size_t)s0 * F_H + f);
    uint4 h1 = *(const uint4*)(h + (size_t)s1 * F_H + f);
    float t0[8], t1[8];
    bf8_to_f32(h0, t0); bf8_to_f32(h1, t1);
#pragma unroll
    for (int i = 0; i < 8; ++i) acc[i] += t0[i] * nr0 + t1[i] * nr1;
  }
  if (j < end) {
    int s = srcs[j];
    float nr = dinv[s] * dn;
    uint4 hv = *(const uint4*)(h + (size_t)s * F_H + f);
    bf8_to_f32(hv, tmp);
#pragma unroll
    for (int i = 0; i < 8; ++i) acc[i] += tmp[i] * nr;
  }

  uint4 o;
  unsigned int r0, r1;
#pragma unroll
  for (int i = 0; i < 8; ++i) {
    acc[i] += bias[f + i];
    acc[i] = fmaxf(acc[i], 0.f);
  }
  r0 = f2bf(acc[0]) | ((unsigned)f2bf(acc[1]) << 16); o.x = r0;
  r1 = f2bf(acc[2]) | ((unsigned)f2bf(acc[3]) << 16); o.y = r1;
  r0 = f2bf(acc[4]) | ((unsigned)f2bf(acc[5]) << 16); o.z = r0;
  r1 = f2bf(acc[6]) | ((unsigned)f2bf(acc[7]) << 16); o.w = r1;
  *(uint4*)(out + (size_t)n * F_H + f) = o;
}

// ---------------- GEMM2 (MFMA bf16): h2 = a1 @ W2, f32 out -----------------
// 256 thr = 4 waves; wave handles 32 rows x 48 cols; B preloaded in regs.
__global__ __launch_bounds__(256) void k_gemm2(const unsigned short* __restrict__ a,
                                               const unsigned short* __restrict__ W2t,
                                               float* __restrict__ h2, int N) {
  const int t = threadIdx.x, lane = t & 63, w = t >> 6;
  const int row0 = blockIdx.x * 128 + w * 32;

  short8 bfr[3][4];
#pragma unroll
  for (int fc = 0; fc < 3; ++fc)
#pragma unroll
    for (int ks = 0; ks < 4; ++ks) {
      int col = fc * 16 + (lane & 15);
      int k = ks * 32 + ((lane >> 4) << 3);
      bfr[fc][ks] = *(const short8*)(W2t + (size_t)col * F_H + k);
    }

  f32x4 acc[2][3];
#pragma unroll
  for (int i = 0; i < 2; ++i)
#pragma unroll
    for (int j = 0; j < 3; ++j) acc[i][j] = (f32x4){0.f, 0.f, 0.f, 0.f};

  short8 af[2][4];
#pragma unroll
  for (int fr = 0; fr < 2; ++fr) {
    int r = row0 + fr * 16 + (lane & 15);
    if (r >= N) r = N - 1;
#pragma unroll
    for (int ks = 0; ks < 4; ++ks) {
      int k = ks * 32 + ((lane >> 4) << 3);
      af[fr][ks] = *(const short8*)(a + (size_t)r * F_H + k);
    }
  }

#pragma unroll
  for (int fr = 0; fr < 2; ++fr)
#pragma unroll
    for (int ks = 0; ks < 4; ++ks)
#pragma unroll
      for (int fc = 0; fc < 3; ++fc)
        acc[fr][fc] = __builtin_amdgcn_mfma_f32_16x16x32_bf16(af[fr][ks], bfr[fc][ks], acc[fr][fc], 0, 0, 0);

#pragma unroll
  for (int fr = 0; fr < 2; ++fr) {
    int rbase = row0 + fr * 16 + ((lane >> 4) << 2);
#pragma unroll
    for (int fc = 0; fc < 3; ++fc) {
      int col = fc * 16 + (lane & 15);
      if (col < F_OUT) {
#pragma unroll
        for (int j = 0; j < 4; ++j) {
          int r = rbase + j;
          if (r < N) h2[(size_t)r * F_OUT + col] = acc[fr][fc][j];
        }
      }
    }
  }
}

// ---------------- CSR gather agg f32 (40-wide), fused +b2 ------------------
__global__ void k_agg40(const float* __restrict__ h, const float* __restrict__ dinv,
                        const int* __restrict__ row_ptr, const int* __restrict__ srcs,
                        const float* __restrict__ bias, float* __restrict__ out, int N) {
  constexpr int CPN = F_OUT / 4;  // 10
  int gid = blockIdx.x * blockDim.x + threadIdx.x;
  int n = gid / CPN;
  if (n >= N) return;
  int f = (gid - n * CPN) * 4;

  float dn = dinv[n];
  float4 acc = *reinterpret_cast<const float4*>(h + (size_t)n * F_OUT + f);
  float sl = dn * dn;
  acc.x *= sl; acc.y *= sl; acc.z *= sl; acc.w *= sl;

  int beg = row_ptr[n], end = row_ptr[n + 1];
  int j = beg;
  for (; j + 1 < end; j += 2) {
    int s0 = srcs[j], s1 = srcs[j + 1];
    float nr0 = dinv[s0] * dn, nr1 = dinv[s1] * dn;
    float4 h0 = *reinterpret_cast<const float4*>(h + (size_t)s0 * F_OUT + f);
    float4 h1 = *reinterpret_cast<const float4*>(h + (size_t)s1 * F_OUT + f);
    acc.x += h0.x * nr0 + h1.x * nr1;
    acc.y += h0.y * nr0 + h1.y * nr1;
    acc.z += h0.z * nr0 + h1.z * nr1;
    acc.w += h0.w * nr0 + h1.w * nr1;
  }
  if (j < end) {
    int s = srcs[j];
    float nr = dinv[s] * dn;
    float4 hv = *reinterpret_cast<const float4*>(h + (size_t)s * F_OUT + f);
    acc.x += hv.x * nr; acc.y += hv.y * nr; acc.z += hv.z * nr; acc.w += hv.w * nr;
  }
  float4 bv = *reinterpret_cast<const float4*>(bias + f);
  acc.x += bv.x; acc.y += bv.y; acc.z += bv.z; acc.w += bv.w;
  *reinterpret_cast<float4*>(out + (size_t)n * F_OUT + f) = acc;
}

// ---------------- log_softmax over 40 classes, in place --------------------
__global__ void k_logsm(float* __restrict__ out, int N) {
  int t = blockIdx.x * blockDim.x + threadIdx.x;
  int n = t >> 6, lane = t & 63;
  if (n >= N) return;
  float val = 0.f, m = -3.0e38f;
  if (lane < F_OUT) { val = out[(size_t)n * F_OUT + lane]; m = val; }
#pragma unroll
  for (int off = 32; off > 0; off >>= 1) m = fmaxf(m, __shfl_xor(m, off));
  float ex = (lane < F_OUT) ? expf(val - m) : 0.f;
#pragma unroll
  for (int off = 32; off > 0; off >>= 1) ex += __shfl_xor(ex, off);
  float ls = logf(ex);
  if (lane < F_OUT) out[(size_t)n * F_OUT + lane] = val - m - ls;
}

extern "C" void kernel_launch(void* const* d_in, const int* in_sizes, int n_in,
                              void* d_out, int out_size, void* d_ws, size_t ws_size,
                              hipStream_t stream) {
  const float* x  = (const float*)d_in[0];
  const int*   ei = (const int*)d_in[1];
  const float* W1 = (const float*)d_in[2];
  const float* b1 = (const float*)d_in[3];
  const float* W2 = (const float*)d_in[4];
  const float* b2 = (const float*)d_in[5];

  const int N = in_sizes[0] / F_IN;   // 50000
  const int E = in_sizes[1] / 2;      // 800000
  const int* src = ei;
  const int* dst = ei + E;

  // workspace layout (4-byte words)
  float* ws   = (float*)d_ws;
  size_t Npad = ((size_t)N + 1023) & ~(size_t)1023;
  float*          dinv   = ws;
  unsigned short* h1b    = (unsigned short*)(ws + Npad);          // N*128 bf16
  unsigned short* a1b    = h1b + (size_t)N * F_H;                 // N*128 bf16
  float*          h2     = (float*)(a1b + (size_t)N * F_H);       // N*40 f32
  int*            cnt    = (int*)(h2 + (size_t)N * F_OUT);
  int*            row_ptr= cnt + Npad;
  int*            cursor = row_ptr + Npad;
  int*            src_sorted = cursor + Npad;
  unsigned short* W1t    = (unsigned short*)(src_sorted + E);     // 128*512 bf16
  unsigned short* W2t    = W1t + (size_t)F_H * F_IN;              // 48*128 bf16
  int*            bsum   = (int*)(W2t + (size_t)F_OP * F_H);
  float*          outp   = (float*)d_out;

  const int B = 256;
  const int nscan = (N + 1023) / 1024;

  k_zero_i32<<<(N + B - 1) / B, B, 0, stream>>>(cnt, N);
  k_count   <<<(E + B - 1) / B, B, 0, stream>>>(dst, cnt, E);
  k_dinv_from_cnt<<<(N + B - 1) / B, B, 0, stream>>>(cnt, dinv, N);
  k_scan_local<<<nscan, 1024, 0, stream>>>(cnt, row_ptr, bsum, N);
  k_scan_carry<<<1, 64, 0, stream>>>(bsum, nscan);
  k_scan_add  <<<(N + 1 + B - 1) / B, B, 0, stream>>>(row_ptr, bsum, N, E);
  k_zero_i32<<<(N + B - 1) / B, B, 0, stream>>>(cursor, N);
  k_scatter <<<(E + B - 1) / B, B, 0, stream>>>(src, dst, row_ptr, cursor, src_sorted, E);

  k_wconv <<<(F_H * F_IN + B - 1) / B, B, 0, stream>>>(W1, W1t);
  k_w2conv<<<(F_OP * F_H + B - 1) / B, B, 0, stream>>>(W2, W2t);

  // layer 1
  k_gemm1<<<(N + 63) / 64, 128, 0, stream>>>(x, W1t, h1b, N);
  {
    long long threads = (long long)N * 16;
    k_agg128<<<(int)((threads + B - 1) / B), B, 0, stream>>>(h1b, dinv, row_ptr, src_sorted, b1, a1b, N);
  }

  // layer 2
  k_gemm2<<<(N + 127) / 128, 256, 0, stream>>>(a1b, W2t, h2, N);
  {
    long long threads = (long long)N * (F_OUT / 4);
    k_agg40<<<(int)((threads + B - 1) / B), B, 0, stream>>>(h2, dinv, row_ptr, src_sorted, b2, outp, N);
  }
  k_logsm<<<((size_t)N * 64 + B - 1) / B, B, 0, stream>>>(outp, N);
}

// Round 5
// 215.896 us; speedup vs baseline: 10.4070x; 1.0561x over previous
//
#include <hip/hip_runtime.h>
#include <cstddef>
#include <cstdint>

typedef __attribute__((ext_vector_type(8))) short short8;
typedef __attribute__((ext_vector_type(4))) float f32x4;

static constexpr int F_IN  = 512;
static constexpr int F_H   = 128;
static constexpr int F_OUT = 40;
static constexpr int F_OP  = 48;   // padded output cols for MFMA

__device__ inline unsigned short f2bf(float f) {
  uint32_t u = __builtin_bit_cast(uint32_t, f);
  u = (u + 0x7FFFu + ((u >> 16) & 1u)) >> 16;
  return (unsigned short)u;
}
__device__ inline float bf2f(uint32_t lo16) {
  return __builtin_bit_cast(float, lo16 << 16);
}
__device__ inline void bf8_to_f32(uint4 u, float* o) {
  o[0] = bf2f(u.x & 0xFFFFu); o[1] = bf2f(u.x >> 16);
  o[2] = bf2f(u.y & 0xFFFFu); o[3] = bf2f(u.y >> 16);
  o[4] = bf2f(u.z & 0xFFFFu); o[5] = bf2f(u.z >> 16);
  o[6] = bf2f(u.w & 0xFFFFu); o[7] = bf2f(u.w >> 16);
}

// ---------------- CSR build ----------------
__global__ void k_zero_i32(int* p, int n) {
  int i = blockIdx.x * blockDim.x + threadIdx.x;
  if (i < n) p[i] = 0;
}

__global__ void k_count(const int* __restrict__ dst, int* __restrict__ cnt, int E) {
  int e = blockIdx.x * blockDim.x + threadIdx.x;
  if (e < E) atomicAdd(&cnt[dst[e]], 1);
}

__global__ void k_dinv_from_cnt(const int* __restrict__ cnt, float* __restrict__ dinv, int N) {
  int i = blockIdx.x * blockDim.x + threadIdx.x;
  if (i < N) dinv[i] = rsqrtf((float)cnt[i] + 1.0f);
}

__global__ void k_scan_local(const int* __restrict__ cnt, int* __restrict__ rp,
                             int* __restrict__ bsum, int N) {
  __shared__ int tmp[1024];
  int t = threadIdx.x;
  int i = blockIdx.x * 1024 + t;
  int v = (i < N) ? cnt[i] : 0;
  tmp[t] = v;
  __syncthreads();
  for (int off = 1; off < 1024; off <<= 1) {
    int u = (t >= off) ? tmp[t - off] : 0;
    __syncthreads();
    tmp[t] += u;
    __syncthreads();
  }
  if (i < N) rp[i] = tmp[t] - v;
  if (t == 1023) bsum[blockIdx.x] = tmp[1023];
}

__global__ void k_scan_carry(int* bsum, int nb) {
  if (threadIdx.x == 0 && blockIdx.x == 0) {
    int run = 0;
    for (int b = 0; b < nb; ++b) { int v = bsum[b]; bsum[b] = run; run += v; }
  }
}

__global__ void k_scan_add(int* __restrict__ rp, const int* __restrict__ bsum, int N, int E) {
  int i = blockIdx.x * blockDim.x + threadIdx.x;
  if (i < N) rp[i] += bsum[i >> 10];
  if (i == N) rp[N] = E;
}

__global__ void k_scatter(const int* __restrict__ src, const int* __restrict__ dst,
                          const int* __restrict__ row_ptr, int* __restrict__ cursor,
                          int* __restrict__ src_sorted, int E) {
  int e = blockIdx.x * blockDim.x + threadIdx.x;
  if (e >= E) return;
  int d = dst[e];
  int pos = row_ptr[d] + atomicAdd(&cursor[d], 1);
  src_sorted[pos] = src[e];
}

// ---------------- W1 [512][128] f32 -> W1t [128][512] bf16 -----------------
__global__ void k_wconv(const float* __restrict__ W, unsigned short* __restrict__ Wt) {
  int i = blockIdx.x * blockDim.x + threadIdx.x;
  if (i >= F_H * F_IN) return;
  int f = i >> 9, k = i & 511;
  Wt[i] = f2bf(W[(size_t)k * F_H + f]);
}

// ---------------- W2 [128][40] f32 -> W2t [48][128] bf16 (zero-padded) -----
__global__ void k_w2conv(const float* __restrict__ W, unsigned short* __restrict__ Wt) {
  int i = blockIdx.x * blockDim.x + threadIdx.x;
  if (i >= F_OP * F_H) return;
  int c = i >> 7, k = i & 127;
  float v = (c < F_OUT) ? W[(size_t)k * F_OUT + c] : 0.f;
  Wt[i] = f2bf(v);
}

// ---------------- GEMM1 (MFMA bf16), 4 waves, double-buffered --------------
// BM=64, BN=128, BK=64. Wave w owns rows w*16..w*16+15 (acc 1x8).
// Per K-tile: issue next-tile global loads -> MFMA current -> convert+ds_write
// next buffer -> barrier. One barrier/iter is safe: buffers alternate.
__global__ __launch_bounds__(256) void k_gemm1(const float* __restrict__ x,
                                               const unsigned short* __restrict__ Wt,
                                               unsigned short* __restrict__ h, int N) {
  __shared__ unsigned short At[2][64][64];     // 16 KB
  __shared__ unsigned short Bt[2][128][64];    // 32 KB
  const int t    = threadIdx.x;
  const int lane = t & 63;
  const int w    = t >> 6;
  const int n0   = blockIdx.x * 64;

  // staging addressing (constant per thread)
  const int arow = t >> 2;                 // 0..63
  const int af0  = (t & 3) * 16;           // float offset in row
  const int alc0 = (t & 3) * 2;            // first of two 8-elt chunks
  int gr = n0 + arow; if (gr >= N) gr = N - 1;
  const float* aptr = x + (size_t)gr * F_IN + af0;

  const int brow = t >> 1;                 // 0..127
  const int bc0  = (t & 1) * 4;            // first of four 8-elt chunks
  const unsigned short* bptr = Wt + (size_t)brow * F_IN + bc0 * 8;

  float4 av0, av1, av2, av3;
  uint4  bv0, bv1, bv2, bv3;

  auto issue = [&](int k0) {
    const float* gp = aptr + k0;
    av0 = *(const float4*)(gp + 0);
    av1 = *(const float4*)(gp + 4);
    av2 = *(const float4*)(gp + 8);
    av3 = *(const float4*)(gp + 12);
    const uint4* bp = (const uint4*)(bptr + k0);
    bv0 = bp[0]; bv1 = bp[1]; bv2 = bp[2]; bv3 = bp[3];
  };

  auto commit = [&](int buf) {
    short8 c0, c1;
    c0[0] = (short)f2bf(av0.x); c0[1] = (short)f2bf(av0.y);
    c0[2] = (short)f2bf(av0.z); c0[3] = (short)f2bf(av0.w);
    c0[4] = (short)f2bf(av1.x); c0[5] = (short)f2bf(av1.y);
    c0[6] = (short)f2bf(av1.z); c0[7] = (short)f2bf(av1.w);
    c1[0] = (short)f2bf(av2.x); c1[1] = (short)f2bf(av2.y);
    c1[2] = (short)f2bf(av2.z); c1[3] = (short)f2bf(av2.w);
    c1[4] = (short)f2bf(av3.x); c1[5] = (short)f2bf(av3.y);
    c1[6] = (short)f2bf(av3.z); c1[7] = (short)f2bf(av3.w);
    *(short8*)&At[buf][arow][((alc0 + 0) ^ (arow & 7)) * 8] = c0;
    *(short8*)&At[buf][arow][((alc0 + 1) ^ (arow & 7)) * 8] = c1;
    *(uint4*)&Bt[buf][brow][((bc0 + 0) ^ (brow & 7)) * 8] = bv0;
    *(uint4*)&Bt[buf][brow][((bc0 + 1) ^ (brow & 7)) * 8] = bv1;
    *(uint4*)&Bt[buf][brow][((bc0 + 2) ^ (brow & 7)) * 8] = bv2;
    *(uint4*)&Bt[buf][brow][((bc0 + 3) ^ (brow & 7)) * 8] = bv3;
  };

  f32x4 acc[8];
#pragma unroll
  for (int j = 0; j < 8; ++j) acc[j] = (f32x4){0.f, 0.f, 0.f, 0.f};

  issue(0);
  commit(0);
  __syncthreads();

  for (int kt = 0; kt < 8; ++kt) {
    const int cur = kt & 1;
    if (kt < 7) issue((kt + 1) * 64);

#pragma unroll
    for (int ks = 0; ks < 2; ++ks) {
      const int lcf = ks * 4 + (lane >> 4);
      const int ar = w * 16 + (lane & 15);
      short8 af = *(const short8*)&At[cur][ar][(lcf ^ (ar & 7)) * 8];
      short8 bfr[8];
#pragma unroll
      for (int fc = 0; fc < 8; ++fc) {
        int r = fc * 16 + (lane & 15);
        bfr[fc] = *(const short8*)&Bt[cur][r][(lcf ^ (r & 7)) * 8];
      }
#pragma unroll
      for (int fc = 0; fc < 8; ++fc)
        acc[fc] = __builtin_amdgcn_mfma_f32_16x16x32_bf16(af, bfr[fc], acc[fc], 0, 0, 0);
    }

    if (kt < 7) commit(cur ^ 1);
    __syncthreads();
  }

  // C write (bf16): col = fc*16 + (lane&15), row = rbase + j
  int rbase = n0 + w * 16 + ((lane >> 4) << 2);
#pragma unroll
  for (int fc = 0; fc < 8; ++fc) {
    int col = fc * 16 + (lane & 15);
#pragma unroll
    for (int j = 0; j < 4; ++j) {
      int r = rbase + j;
      if (r < N) h[(size_t)r * F_H + col] = f2bf(acc[fc][j]);
    }
  }
}

// ---------------- CSR gather agg bf16->bf16 (128-wide), fused bias+ReLU ----
__global__ void k_agg128(const unsigned short* __restrict__ h, const float* __restrict__ dinv,
                         const int* __restrict__ row_ptr, const int* __restrict__ srcs,
                         const float* __restrict__ bias, unsigned short* __restrict__ out, int N) {
  int gid = blockIdx.x * blockDim.x + threadIdx.x;
  int n = gid >> 4;
  if (n >= N) return;
  int f = (gid & 15) * 8;

  float dn = dinv[n];
  float acc[8], tmp[8];
  uint4 sv = *(const uint4*)(h + (size_t)n * F_H + f);
  bf8_to_f32(sv, tmp);
  float sl = dn * dn;
#pragma unroll
  for (int i = 0; i < 8; ++i) acc[i] = tmp[i] * sl;

  int beg = row_ptr[n], end = row_ptr[n + 1];
  int j = beg;
  for (; j + 1 < end; j += 2) {
    int s0 = srcs[j], s1 = srcs[j + 1];
    float nr0 = dinv[s0] * dn, nr1 = dinv[s1] * dn;
    uint4 h0 = *(const uint4*)(h + (size_t)s0 * F_H + f);
    uint4 h1 = *(const uint4*)(h + (size_t)s1 * F_H + f);
    float t0[8], t1[8];
    bf8_to_f32(h0, t0); bf8_to_f32(h1, t1);
#pragma unroll
    for (int i = 0; i < 8; ++i) acc[i] += t0[i] * nr0 + t1[i] * nr1;
  }
  if (j < end) {
    int s = srcs[j];
    float nr = dinv[s] * dn;
    uint4 hv = *(const uint4*)(h + (size_t)s * F_H + f);
    bf8_to_f32(hv, tmp);
#pragma unroll
    for (int i = 0; i < 8; ++i) acc[i] += tmp[i] * nr;
  }

  uint4 o;
  unsigned int r0, r1;
#pragma unroll
  for (int i = 0; i < 8; ++i) {
    acc[i] += bias[f + i];
    acc[i] = fmaxf(acc[i], 0.f);
  }
  r0 = f2bf(acc[0]) | ((unsigned)f2bf(acc[1]) << 16); o.x = r0;
  r1 = f2bf(acc[2]) | ((unsigned)f2bf(acc[3]) << 16); o.y = r1;
  r0 = f2bf(acc[4]) | ((unsigned)f2bf(acc[5]) << 16); o.z = r0;
  r1 = f2bf(acc[6]) | ((unsigned)f2bf(acc[7]) << 16); o.w = r1;
  *(uint4*)(out + (size_t)n * F_H + f) = o;
}

// ---------------- GEMM2 (MFMA bf16): h2 = a1 @ W2, f32 out -----------------
__global__ __launch_bounds__(256) void k_gemm2(const unsigned short* __restrict__ a,
                                               const unsigned short* __restrict__ W2t,
                                               float* __restrict__ h2, int N) {
  const int t = threadIdx.x, lane = t & 63, w = t >> 6;
  const int row0 = blockIdx.x * 128 + w * 32;

  short8 bfr[3][4];
#pragma unroll
  for (int fc = 0; fc < 3; ++fc)
#pragma unroll
    for (int ks = 0; ks < 4; ++ks) {
      int col = fc * 16 + (lane & 15);
      int k = ks * 32 + ((lane >> 4) << 3);
      bfr[fc][ks] = *(const short8*)(W2t + (size_t)col * F_H + k);
    }

  f32x4 acc[2][3];
#pragma unroll
  for (int i = 0; i < 2; ++i)
#pragma unroll
    for (int j = 0; j < 3; ++j) acc[i][j] = (f32x4){0.f, 0.f, 0.f, 0.f};

  short8 af[2][4];
#pragma unroll
  for (int fr = 0; fr < 2; ++fr) {
    int r = row0 + fr * 16 + (lane & 15);
    if (r >= N) r = N - 1;
#pragma unroll
    for (int ks = 0; ks < 4; ++ks) {
      int k = ks * 32 + ((lane >> 4) << 3);
      af[fr][ks] = *(const short8*)(a + (size_t)r * F_H + k);
    }
  }

#pragma unroll
  for (int fr = 0; fr < 2; ++fr)
#pragma unroll
    for (int ks = 0; ks < 4; ++ks)
#pragma unroll
      for (int fc = 0; fc < 3; ++fc)
        acc[fr][fc] = __builtin_amdgcn_mfma_f32_16x16x32_bf16(af[fr][ks], bfr[fc][ks], acc[fr][fc], 0, 0, 0);

#pragma unroll
  for (int fr = 0; fr < 2; ++fr) {
    int rbase = row0 + fr * 16 + ((lane >> 4) << 2);
#pragma unroll
    for (int fc = 0; fc < 3; ++fc) {
      int col = fc * 16 + (lane & 15);
      if (col < F_OUT) {
#pragma unroll
        for (int j = 0; j < 4; ++j) {
          int r = rbase + j;
          if (r < N) h2[(size_t)r * F_OUT + col] = acc[fr][fc][j];
        }
      }
    }
  }
}

// ---------------- CSR gather agg f32 (40-wide), fused +b2 ------------------
__global__ void k_agg40(const float* __restrict__ h, const float* __restrict__ dinv,
                        const int* __restrict__ row_ptr, const int* __restrict__ srcs,
                        const float* __restrict__ bias, float* __restrict__ out, int N) {
  constexpr int CPN = F_OUT / 4;  // 10
  int gid = blockIdx.x * blockDim.x + threadIdx.x;
  int n = gid / CPN;
  if (n >= N) return;
  int f = (gid - n * CPN) * 4;

  float dn = dinv[n];
  float4 acc = *reinterpret_cast<const float4*>(h + (size_t)n * F_OUT + f);
  float sl = dn * dn;
  acc.x *= sl; acc.y *= sl; acc.z *= sl; acc.w *= sl;

  int beg = row_ptr[n], end = row_ptr[n + 1];
  int j = beg;
  for (; j + 1 < end; j += 2) {
    int s0 = srcs[j], s1 = srcs[j + 1];
    float nr0 = dinv[s0] * dn, nr1 = dinv[s1] * dn;
    float4 h0 = *reinterpret_cast<const float4*>(h + (size_t)s0 * F_OUT + f);
    float4 h1 = *reinterpret_cast<const float4*>(h + (size_t)s1 * F_OUT + f);
    acc.x += h0.x * nr0 + h1.x * nr1;
    acc.y += h0.y * nr0 + h1.y * nr1;
    acc.z += h0.z * nr0 + h1.z * nr1;
    acc.w += h0.w * nr0 + h1.w * nr1;
  }
  if (j < end) {
    int s = srcs[j];
    float nr = dinv[s] * dn;
    float4 hv = *reinterpret_cast<const float4*>(h + (size_t)s * F_OUT + f);
    acc.x += hv.x * nr; acc.y += hv.y * nr; acc.z += hv.z * nr; acc.w += hv.w * nr;
  }
  float4 bv = *reinterpret_cast<const float4*>(bias + f);
  acc.x += bv.x; acc.y += bv.y; acc.z += bv.z; acc.w += bv.w;
  *reinterpret_cast<float4*>(out + (size_t)n * F_OUT + f) = acc;
}

// ---------------- log_softmax over 40 classes, in place --------------------
__global__ void k_logsm(float* __restrict__ out, int N) {
  int t = blockIdx.x * blockDim.x + threadIdx.x;
  int n = t >> 6, lane = t & 63;
  if (n >= N) return;
  float val = 0.f, m = -3.0e38f;
  if (lane < F_OUT) { val = out[(size_t)n * F_OUT + lane]; m = val; }
#pragma unroll
  for (int off = 32; off > 0; off >>= 1) m = fmaxf(m, __shfl_xor(m, off));
  float ex = (lane < F_OUT) ? expf(val - m) : 0.f;
#pragma unroll
  for (int off = 32; off > 0; off >>= 1) ex += __shfl_xor(ex, off);
  float ls = logf(ex);
  if (lane < F_OUT) out[(size_t)n * F_OUT + lane] = val - m - ls;
}

extern "C" void kernel_launch(void* const* d_in, const int* in_sizes, int n_in,
                              void* d_out, int out_size, void* d_ws, size_t ws_size,
                              hipStream_t stream) {
  const float* x  = (const float*)d_in[0];
  const int*   ei = (const int*)d_in[1];
  const float* W1 = (const float*)d_in[2];
  const float* b1 = (const float*)d_in[3];
  const float* W2 = (const float*)d_in[4];
  const float* b2 = (const float*)d_in[5];

  const int N = in_sizes[0] / F_IN;   // 50000
  const int E = in_sizes[1] / 2;      // 800000
  const int* src = ei;
  const int* dst = ei + E;

  // workspace layout (4-byte words)
  float* ws   = (float*)d_ws;
  size_t Npad = ((size_t)N + 1023) & ~(size_t)1023;
  float*          dinv   = ws;
  unsigned short* h1b    = (unsigned short*)(ws + Npad);          // N*128 bf16
  unsigned short* a1b    = h1b + (size_t)N * F_H;                 // N*128 bf16
  float*          h2     = (float*)(a1b + (size_t)N * F_H);       // N*40 f32
  int*            cnt    = (int*)(h2 + (size_t)N * F_OUT);
  int*            row_ptr= cnt + Npad;
  int*            cursor = row_ptr + Npad;
  int*            src_sorted = cursor + Npad;
  unsigned short* W1t    = (unsigned short*)(src_sorted + E);     // 128*512 bf16
  unsigned short* W2t    = W1t + (size_t)F_H * F_IN;              // 48*128 bf16
  int*            bsum   = (int*)(W2t + (size_t)F_OP * F_H);
  float*          outp   = (float*)d_out;

  const int B = 256;
  const int nscan = (N + 1023) / 1024;

  k_zero_i32<<<(N + B - 1) / B, B, 0, stream>>>(cnt, N);
  k_count   <<<(E + B - 1) / B, B, 0, stream>>>(dst, cnt, E);
  k_dinv_from_cnt<<<(N + B - 1) / B, B, 0, stream>>>(cnt, dinv, N);
  k_scan_local<<<nscan, 1024, 0, stream>>>(cnt, row_ptr, bsum, N);
  k_scan_carry<<<1, 64, 0, stream>>>(bsum, nscan);
  k_scan_add  <<<(N + 1 + B - 1) / B, B, 0, stream>>>(row_ptr, bsum, N, E);
  k_zero_i32<<<(N + B - 1) / B, B, 0, stream>>>(cursor, N);
  k_scatter <<<(E + B - 1) / B, B, 0, stream>>>(src, dst, row_ptr, cursor, src_sorted, E);

  k_wconv <<<(F_H * F_IN + B - 1) / B, B, 0, stream>>>(W1, W1t);
  k_w2conv<<<(F_OP * F_H + B - 1) / B, B, 0, stream>>>(W2, W2t);

  // layer 1
  k_gemm1<<<(N + 63) / 64, 256, 0, stream>>>(x, W1t, h1b, N);
  {
    long long threads = (long long)N * 16;
    k_agg128<<<(int)((threads + B - 1) / B), B, 0, stream>>>(h1b, dinv, row_ptr, src_sorted, b1, a1b, N);
  }

  // layer 2
  k_gemm2<<<(N + 127) / 128, 256, 0, stream>>>(a1b, W2t, h2, N);
  {
    long long threads = (long long)N * (F_OUT / 4);
    k_agg40<<<(int)((threads + B - 1) / B), B, 0, stream>>>(h2, dinv, row_ptr, src_sorted, b2, outp, N);
  }
  k_logsm<<<((size_t)N * 64 + B - 1) / B, B, 0, stream>>>(outp, N);
}